// Round 1
// baseline (428.473 us; speedup 1.0000x reference)
//
#include <hip/hip_runtime.h>

#define KS   21
#define HALO 10
#define TH   24              // 4 waves x 6 rows per thread
#define TW   256
#define R    6               // output rows per thread
#define PH   (TH + 2*HALO)   // 44
#define PW   276             // 256 + 20, rows 16B-aligned (1104 B)
#define HDIM 768

__device__ __forceinline__ int reflect_idx(int x, int n) {
    if (x < 0) x = -x;
    if (x >= n) x = 2 * n - 2 - x;
    return x;
}

__global__ __launch_bounds__(256, 3)
void blur_by_kernel(const float* __restrict__ in,
                    const float* __restrict__ kern,
                    float* __restrict__ out) {
    __shared__ float tile[PH * PW];   // 48.6 KB -> 3 blocks/CU

    const int bx  = blockIdx.x;   // 0..2   col tile
    const int by  = blockIdx.y;   // 0..31  row tile
    const int bc  = blockIdx.z;   // b*3+c
    const int b   = bc / 3;
    const int tid = threadIdx.x;
    const int lane = tid & 63;
    const int w    = tid >> 6;    // wave id -> output rows R*w .. R*w+R-1

    const float* plane = in + (size_t)bc * (HDIM * HDIM);
    const int y0 = by * TH - HALO;
    const int x0 = bx * TW - HALO;

    for (int idx = tid; idx < PH * PW; idx += 256) {
        int r = idx / PW;
        int c = idx - r * PW;
        tile[idx] = plane[reflect_idx(y0 + r, HDIM) * HDIM + reflect_idx(x0 + c, HDIM)];
    }
    __syncthreads();

    const float* kb = kern + b * (KS * KS);  // block-uniform -> scalar loads

    float acc[R][4] = {};
    float4 xA[6], xB[6];
    const int colbase = lane * 4;

    // all 64 lanes read the SAME padded row: wave-uniform base + contiguous
    // 16B/lane (6 overlapping ds_read_b128 per lane = exactly the 24 floats
    // this lane's 4-col window needs)
    #define LOADROW(buf, t)                                                    \
        {                                                                      \
            const float4* lrow = (const float4*)&tile[(w * R + (t)) * PW + colbase]; \
            _Pragma("unroll")                                                  \
            for (int j = 0; j < 6; ++j) buf[j] = lrow[j];                      \
        }

    #define FMAROW(buf, r, ki)                                                \
        {                                                                      \
            const float* xs_ = (const float*)(buf);                           \
            const float* krow = kb + (ki) * KS;                               \
            _Pragma("unroll")                                                 \
            for (int kj = 0; kj < KS; ++kj) {                                 \
                float kv = krow[kj];                                          \
                _Pragma("unroll")                                             \
                for (int c = 0; c < 4; ++c)                                   \
                    acc[r][c] = fmaf(kv, xs_[kj + c], acc[r][c]);             \
            }                                                                 \
        }

    // all R rows valid (steady state), runtime t
    #define FMAS_ALL(buf, t)                                                  \
        {                                                                      \
            _Pragma("unroll")                                                 \
            for (int r = 0; r < R; ++r) FMAROW(buf, r, (t) - r);              \
        }

    // compile-time t: only rows with 0 <= t-r <= 20 (folds at compile time)
    #define FMAS_P(buf, t)                                                    \
        {                                                                      \
            _Pragma("unroll")                                                 \
            for (int r = 0; r < R; ++r)                                       \
                if ((t) - r >= 0 && (t) - r <= KS - 1) FMAROW(buf, r, (t) - r); \
        }

    // ---- ramp: t = 0..4, pipelined A/B, partial rows (compile-time) ----
    LOADROW(xA, 0);
    LOADROW(xB, 1);  FMAS_P(xA, 0);
    LOADROW(xA, 2);  FMAS_P(xB, 1);
    LOADROW(xB, 3);  FMAS_P(xA, 2);
    LOADROW(xA, 4);  FMAS_P(xB, 3);
    LOADROW(xB, 5);  FMAS_P(xA, 4);

    // ---- steady: t = 5..20, all R rows valid, double-buffered ----
    // each LOADROW is issued one full FMA block (~500 FMAs) before its use:
    // LDS latency + bank-conflict cycles hide under compute
    #pragma unroll 1
    for (int t = 5; t < 20; t += 2) {
        LOADROW(xA, t + 1);
        FMAS_ALL(xB, t);
        LOADROW(xB, t + 2);          // t=19 -> row 21 (valid, first drain row)
        FMAS_ALL(xA, t + 1);
    }

    // ---- drain: t = 21..25, xB holds row 21 on entry ----
    LOADROW(xA, 22); FMAS_P(xB, 21);
    LOADROW(xB, 23); FMAS_P(xA, 22);
    LOADROW(xA, 24); FMAS_P(xB, 23);
    LOADROW(xB, 25); FMAS_P(xA, 24);
    FMAS_P(xB, 25);

    float* oplane = out + (size_t)bc * (HDIM * HDIM);
    const int gx = bx * TW + colbase;
    const int gy = by * TH + w * R;
    #pragma unroll
    for (int r = 0; r < R; ++r) {
        float4 v = make_float4(acc[r][0], acc[r][1], acc[r][2], acc[r][3]);
        *(float4*)&oplane[(size_t)(gy + r) * HDIM + gx] = v;
    }
}

extern "C" void kernel_launch(void* const* d_in, const int* in_sizes, int n_in,
                              void* d_out, int out_size, void* d_ws, size_t ws_size,
                              hipStream_t stream) {
    const float* in   = (const float*)d_in[0];   // (16,3,768,768) fp32
    const float* kern = (const float*)d_in[1];   // (16,21,21) fp32
    float* out = (float*)d_out;

    dim3 grid(HDIM / TW, HDIM / TH, 16 * 3);     // 3 x 32 x 48
    dim3 block(256);
    blur_by_kernel<<<grid, block, 0, stream>>>(in, kern, out);
}